// Round 3
// 279.627 us; speedup vs baseline: 1.0094x; 1.0094x over previous
//
#include <hip/hip_runtime.h>

// clang-native 4-float vector: __builtin_nontemporal_store requires a native
// vector type (HIP's float4 is a class and is rejected by the builtin).
typedef float f32x4 __attribute__((ext_vector_type(4)));

// Fixed-point quantize to (int_bits=6, frac_bits=10):
// round-half-even to 2^-10 grid, clamp to [-64, 64 - 2^-10].
// rintf == v_rndne_f32 (nearest-even) matches jnp.round semantics.
__device__ __forceinline__ float fpq10(float x) {
    float r = rintf(x * 1024.0f) * 0.0009765625f;  // /1024 exact (pow2)
    r = fmaxf(r, -64.0f);
    r = fminf(r, 63.9990234375f);
    return r;
}

#define PTS 256      // points per block == block size
#define PAD 17       // odd stride -> conflict-free b32 LDS writes (gcd(17,32)=1);
                     // total LDS 3+17 KB = 20 KB -> 8 blocks/CU = 32 waves (max occupancy)

__global__ __launch_bounds__(256, 8) void qsh_kernel(const float* __restrict__ in,
                                                     float* __restrict__ out,
                                                     int n) {
    __shared__ float s_in[3 * PTS];        // 3 KB
    __shared__ float s_out[PTS * PAD];     // 17 KB

    const int t = threadIdx.x;
    const long long blockStart = (long long)blockIdx.x * PTS;
    const long long inBase = blockStart * 3;
    const long long nIn = (long long)n * 3;

    // ---- stage input: coalesced global reads (lane stride 4 B), nt policy ----
#pragma unroll
    for (int k = 0; k < 3; ++k) {
        long long gi = inBase + k * PTS + t;
        s_in[k * PTS + t] = (gi < nIn) ? __builtin_nontemporal_load(in + gi) : 0.0f;
    }
    __syncthreads();

    // per-point values: addresses 3t,3t+1,3t+2 -> 2-way bank aliasing (free)
    float u = s_in[3 * t + 0];
    float v = s_in[3 * t + 1];
    float w = s_in[3 * t + 2];

    // u*2-1 may contract to fma; u*2 is exact so result is bit-identical either way.
    float x = fpq10(u * 2.0f - 1.0f);
    float y = fpq10(v * 2.0f - 1.0f);
    float z = fpq10(w * 2.0f - 1.0f);
    float xy = fpq10(x * y);
    float xz = fpq10(x * z);
    float yz = fpq10(y * z);
    float x2 = fpq10(x * x);
    float y2 = fpq10(y * y);
    float z2 = fpq10(z * z);

    // qc(c) = fpq(float32(c)) precomputed (k/1024 values, hand-verified):
    const float C0  = 0.2822265625f;   // 289/1024
    const float C1  = 0.48828125f;     // 500/1024
    const float C2  = 1.0927734375f;   // 1119/1024
    const float C3  = 0.9462890625f;   // 969/1024
    const float C4  = 0.3154296875f;   // 323/1024
    const float C5  = 0.5458984375f;   // 559/1024
    const float C6  = 0.58984375f;     // 604/1024
    const float C7  = 2.890625f;       // 2960/1024
    const float C8  = 0.45703125f;     // 468/1024
    const float C9  = 0.373046875f;    // 382/1024
    const float C10 = 1.4453125f;      // 1480/1024

    float o0  = C0;
    float o1  = fpq10(-C1 * fpq10(y));
    float o2  = fpq10( C1 * fpq10(z));
    float o3  = fpq10(-C1 * fpq10(x));
    float o4  = fpq10( C2 * fpq10(xy));
    float o5  = fpq10(-C2 * fpq10(yz));
    float o6  = fpq10( C3 * fpq10(z2) - C4);
    float o7  = fpq10(-C2 * fpq10(xz));
    float o8  = fpq10( C5 * fpq10(x2) - C5 * fpq10(y2));
    // triple products: jnp evaluates left-to-right ((qc*qf(a))*qf(b))
    float o9  = fpq10((C6  * fpq10(y)) * fpq10(-3.0f * x2 + y2));
    float o10 = fpq10((C7  * fpq10(xy)) * fpq10(z));
    float o11 = fpq10((C8  * fpq10(y)) * fpq10(1.0f - 5.0f * z2));
    float o12 = fpq10((C9  * fpq10(z)) * fpq10(5.0f * z2 - 3.0f));
    float o13 = fpq10((C8  * fpq10(x)) * fpq10(1.0f - 5.0f * z2));
    float o14 = fpq10((C10 * fpq10(z)) * fpq10(x2 - y2));
    float o15 = fpq10((C6  * fpq10(x)) * fpq10(-x2 + 3.0f * y2));

    // ---- stage output to LDS: 16 b32 writes at odd stride (conflict-free) ----
    float* so = &s_out[t * PAD];
    so[0]  = o0;  so[1]  = o1;  so[2]  = o2;  so[3]  = o3;
    so[4]  = o4;  so[5]  = o5;  so[6]  = o6;  so[7]  = o7;
    so[8]  = o8;  so[9]  = o9;  so[10] = o10; so[11] = o11;
    so[12] = o12; so[13] = o13; so[14] = o14; so[15] = o15;
    __syncthreads();

    // ---- coalesced write-out: 1024 float4s per block, lane stride 16 B, nt policy ----
    const long long outBase4 = blockStart * 4;        // global float4 index base
    const long long nOut4 = (long long)n * 4;
    f32x4* outv = reinterpret_cast<f32x4*>(out);
#pragma unroll
    for (int k = 0; k < 4; ++k) {
        long long f = outBase4 + k * PTS + t;
        if (f < nOut4) {
            int lf = k * PTS + t;                     // local float4 idx 0..1023
            int p = lf >> 2;                          // point within block
            int q = lf & 3;                           // float4 chunk within point
            const float* sp = &s_out[p * PAD + q * 4];
            f32x4 val = {sp[0], sp[1], sp[2], sp[3]};
            __builtin_nontemporal_store(val, &outv[f]);
        }
    }
}

extern "C" void kernel_launch(void* const* d_in, const int* in_sizes, int n_in,
                              void* d_out, int out_size, void* d_ws, size_t ws_size,
                              hipStream_t stream) {
    const float* in = (const float*)d_in[0];
    float* out = (float*)d_out;
    int n = in_sizes[0] / 3;           // [N,3] flat
    int grid = (n + PTS - 1) / PTS;
    qsh_kernel<<<grid, PTS, 0, stream>>>(in, out, n);
}

// Round 4
// 279.410 us; speedup vs baseline: 1.0102x; 1.0008x over previous
//
#include <hip/hip_runtime.h>

// clang-native 4-float vector: __builtin_nontemporal_store requires a native
// vector type (HIP's float4 is a class and is rejected by the builtin).
typedef float f32x4 __attribute__((ext_vector_type(4)));

// Fixed-point quantize to (int_bits=6, frac_bits=10):
// round-half-even to 2^-10 grid, clamp to [-64, 64 - 2^-10].
// rintf == v_rndne_f32 (nearest-even) matches jnp.round semantics.
__device__ __forceinline__ float fpq10(float x) {
    float r = rintf(x * 1024.0f) * 0.0009765625f;  // /1024 exact (pow2)
    r = fmaxf(r, -64.0f);
    r = fminf(r, 63.9990234375f);
    return r;
}

#define PTS 256      // points per block == block size
#define PAD 17       // odd stride -> conflict-free b32 LDS writes (gcd(17,32)=1);
                     // total LDS 3+17 KB = 20 KB -> LDS allows 8 blocks/CU

// launch_bounds(256,4): VGPR cap 128 (was 8 -> cap 64, suspected scratch spills;
// spill traffic ~4M threads x ~80B would explain the 2.5 TB/s effective BW).
// If kernel fits <=64 VGPR anyway, occupancy is unchanged -> clean A/B.
__global__ __launch_bounds__(256, 4) void qsh_kernel(const float* __restrict__ in,
                                                     float* __restrict__ out,
                                                     int n) {
    __shared__ float s_in[3 * PTS];        // 3 KB
    __shared__ float s_out[PTS * PAD];     // 17 KB

    const int t = threadIdx.x;
    const long long blockStart = (long long)blockIdx.x * PTS;
    const long long inBase = blockStart * 3;
    const long long nIn = (long long)n * 3;

    // ---- stage input: coalesced global reads (lane stride 4 B), nt policy ----
#pragma unroll
    for (int k = 0; k < 3; ++k) {
        long long gi = inBase + k * PTS + t;
        s_in[k * PTS + t] = (gi < nIn) ? __builtin_nontemporal_load(in + gi) : 0.0f;
    }
    __syncthreads();

    // per-point values: addresses 3t,3t+1,3t+2 -> 2-way bank aliasing (free)
    float u = s_in[3 * t + 0];
    float v = s_in[3 * t + 1];
    float w = s_in[3 * t + 2];

    // u*2-1 may contract to fma; u*2 is exact so result is bit-identical either way.
    float x = fpq10(u * 2.0f - 1.0f);
    float y = fpq10(v * 2.0f - 1.0f);
    float z = fpq10(w * 2.0f - 1.0f);
    float xy = fpq10(x * y);
    float xz = fpq10(x * z);
    float yz = fpq10(y * z);
    float x2 = fpq10(x * x);
    float y2 = fpq10(y * y);
    float z2 = fpq10(z * z);

    // qc(c) = fpq(float32(c)) precomputed (k/1024 values, hand-verified):
    const float C0  = 0.2822265625f;   // 289/1024
    const float C1  = 0.48828125f;     // 500/1024
    const float C2  = 1.0927734375f;   // 1119/1024
    const float C3  = 0.9462890625f;   // 969/1024
    const float C4  = 0.3154296875f;   // 323/1024
    const float C5  = 0.5458984375f;   // 559/1024
    const float C6  = 0.58984375f;     // 604/1024
    const float C7  = 2.890625f;       // 2960/1024
    const float C8  = 0.45703125f;     // 468/1024
    const float C9  = 0.373046875f;    // 382/1024
    const float C10 = 1.4453125f;      // 1480/1024

    // NOTE: fpq10(v) for v in {x,y,z,xy,xz,yz,x2,y2,z2} is bit-exactly the
    // identity (v is already on the 2^-10 grid and inside the clamp range:
    // v*1024 is an exact small integer in f32, rintf is a no-op, /1024 exact,
    // clamps no-op). The reference's qf() re-quantizations of these variables
    // are therefore dropped. fpq10 on COMPOUND expressions (-3x2+y2, 1-5z2,
    // 5z2-3, x2-y2, -x2+3y2) is kept: those can leave the clamp range.
    float o0  = C0;
    float o1  = fpq10(-C1 * y);
    float o2  = fpq10( C1 * z);
    float o3  = fpq10(-C1 * x);
    float o4  = fpq10( C2 * xy);
    float o5  = fpq10(-C2 * yz);
    float o6  = fpq10( C3 * z2 - C4);
    float o7  = fpq10(-C2 * xz);
    float o8  = fpq10( C5 * x2 - C5 * y2);
    // triple products: jnp evaluates left-to-right ((qc*qf(a))*qf(b))
    float o9  = fpq10((C6  * y) * fpq10(-3.0f * x2 + y2));
    float o10 = fpq10((C7  * xy) * z);
    float o11 = fpq10((C8  * y) * fpq10(1.0f - 5.0f * z2));
    float o12 = fpq10((C9  * z) * fpq10(5.0f * z2 - 3.0f));
    float o13 = fpq10((C8  * x) * fpq10(1.0f - 5.0f * z2));
    float o14 = fpq10((C10 * z) * fpq10(x2 - y2));
    float o15 = fpq10((C6  * x) * fpq10(-x2 + 3.0f * y2));

    // ---- stage output to LDS: 16 b32 writes at odd stride (conflict-free) ----
    float* so = &s_out[t * PAD];
    so[0]  = o0;  so[1]  = o1;  so[2]  = o2;  so[3]  = o3;
    so[4]  = o4;  so[5]  = o5;  so[6]  = o6;  so[7]  = o7;
    so[8]  = o8;  so[9]  = o9;  so[10] = o10; so[11] = o11;
    so[12] = o12; so[13] = o13; so[14] = o14; so[15] = o15;
    __syncthreads();

    // ---- coalesced write-out: 1024 float4s per block, lane stride 16 B, nt policy ----
    const long long outBase4 = blockStart * 4;        // global float4 index base
    const long long nOut4 = (long long)n * 4;
    f32x4* outv = reinterpret_cast<f32x4*>(out);
#pragma unroll
    for (int k = 0; k < 4; ++k) {
        long long f = outBase4 + k * PTS + t;
        if (f < nOut4) {
            int lf = k * PTS + t;                     // local float4 idx 0..1023
            int p = lf >> 2;                          // point within block
            int q = lf & 3;                           // float4 chunk within point
            const float* sp = &s_out[p * PAD + q * 4];
            f32x4 val = {sp[0], sp[1], sp[2], sp[3]};
            __builtin_nontemporal_store(val, &outv[f]);
        }
    }
}

extern "C" void kernel_launch(void* const* d_in, const int* in_sizes, int n_in,
                              void* d_out, int out_size, void* d_ws, size_t ws_size,
                              hipStream_t stream) {
    const float* in = (const float*)d_in[0];
    float* out = (float*)d_out;
    int n = in_sizes[0] / 3;           // [N,3] flat
    int grid = (n + PTS - 1) / PTS;
    qsh_kernel<<<grid, PTS, 0, stream>>>(in, out, n);
}